// Round 7
// baseline (949.998 us; speedup 1.0000x reference)
//
#include <hip/hip_runtime.h>
#include <math.h>

#define T_TOK 16384   // 4*4096 tokens
#define NEXP  64

// Workspace layout (floats):
//   ws[0..63]   : expert load sums
//   ws[64]      : sum of z^2
//   ws[66]      : block-done counter (int)
//   ws[128 ..]  : w_t transposed gate weights [1024][64]
//
// d_out layout (floats, out_size = 65537):
//   [0, 32768)      top-2 renormalized scores [token][2]
//   [32768, 65536)  top-2 expert indices as floats [token][2]
//   [65536]         total_loss

// ---------------------------------------------------------------------------
// prep: tiled transpose gate_w [64][1024] -> w_t [1024][64]; zero accumulators
// ---------------------------------------------------------------------------
__global__ void moe_prep(const float* __restrict__ gw, float* __restrict__ ws) {
    __shared__ float tile[64][65];
    const int b = blockIdx.x;
    const int tid = threadIdx.x;         // 256
    if (b == 0 && tid < 128) ws[tid] = 0.f;
#pragma unroll
    for (int it = 0; it < 16; ++it) {
        int idx = it * 256 + tid;
        int e = idx >> 6, kk = idx & 63;
        tile[e][kk] = gw[e * 1024 + b * 64 + kk];
    }
    __syncthreads();
#pragma unroll
    for (int it = 0; it < 16; ++it) {
        int idx = it * 256 + tid;
        int kk = idx >> 6, e = idx & 63;
        ws[128 + (b * 64 + kk) * 64 + e] = tile[e][kk];
    }
}

// direct global->LDS DMA, 16 B per lane, zero VGPR staging cost
__device__ __forceinline__ void gl_lds16(const float* g, float* l) {
    __builtin_amdgcn_global_load_lds(
        (const __attribute__((address_space(1))) void*)g,
        (__attribute__((address_space(3))) void*)l, 16, 0, 0);
}

// ---------------------------------------------------------------------------
// main: fat-step GEMM (K_STEP=256, 4 steps, 8 barriers) with ZERO-REGISTER
// staging. Rounds 5/6 post-mortem: the toolchain hard-caps the allocator at
// 64 arch-VGPRs (launch_bounds 2nd arg ignored); the 32 prefetch regs of the
// global->reg->LDS round-trip forced a 93 MB scratch spill and the fat-step
// theory never got tested. Fix: global_load_lds DMA (no staging VGPRs).
// LDS dest is wave-uniform+linear (HW constraint), so the x bank-swizzle is
// applied by PRE-SWIZZLING the per-lane GLOBAL source granule (g ^ (row&15));
// the read side keeps the proven XOR -> data placement, k-quarter ownership,
// summation tree, fold and epilogue are bit-identical to the absmax-0 proven
// kernels (r0/r5 lineage). Live set ~56 VGPR < 64 cap -> no spill
// (tripwire: WRITE_SIZE must be ~0.34 MB).
// ---------------------------------------------------------------------------
__launch_bounds__(1024, 4)
__global__ void moe_main(const float* __restrict__ x,
                         const float* __restrict__ wt,     // [1024][64]
                         float* __restrict__ acc_ws,
                         float* __restrict__ out) {
    __shared__ float xbuf[64 * 256];     // x slab: [t 64][q 4][g 16 ^ swz][4]
    __shared__ float wbuf[256 * 64];     // w slab: [krow 256][e 64] straight
    __shared__ float sc[64 * 68];        // logits, stride 68
    __shared__ float row_inv[64];
    __shared__ float colpart[16][64];
    __shared__ int   is_last;

    const int tid  = threadIdx.x;
    const int lane = tid & 63;
    const int wv   = tid >> 6;                                   // 0..15
    const int wvu  = __builtin_amdgcn_readfirstlane(wv);         // uniform copy
    const int kq   = __builtin_amdgcn_readfirstlane(wv & 3);     // k quarter
    const int tile = __builtin_amdgcn_readfirstlane(wv >> 2);    // (t,e) tile
    const int tt = tile >> 1, te = tile & 1;
    const int ta = lane >> 3;            // token-quad within tile (0..7)
    const int eb = lane & 7;             // expert-quad within tile (0..7)
    const int tok0 = blockIdx.x << 6;

    // ---- DMA staging plan: per wave, 4 x-issues + 4 w-issues per step.
    // x issue i: token row tr = wvu*4+i; chunk = xbuf + tr*256; lane writes
    //   floats [lane*4,+4) = quarter (lane>>4), slot (lane&15). Source granule
    //   pre-swizzled: slot g holds global granule g ^ (tr&15). Since
    //   (wvu*4+i)&15 = (wvu&3)*4 + i and i<4: swz granule = (g_l^(wvu&3)*4)^i.
    // w issue i: chunk = wbuf + (wvu*4+i)*256 = slab rows [c*4,c*4+4);
    //   slab row r holds global k-row (r>>6)*256 + s*64 + (r&63) (straight).
    const int q_l = lane >> 4;
    const int g_l = lane & 15;
    const int g0  = g_l ^ ((wvu & 3) << 2);
    const float* gxB = x + (((size_t)(tok0 + (wvu << 2))) << 10) + (q_l << 8);
    const float* gwB = wt + ((((wvu >> 2) << 8) + ((wvu & 3) << 4) + q_l) << 6)
                          + (g_l << 2);
    float* xl0 = xbuf + (wvu << 10);     // wave's x chunk base (wvu*4 rows *256)
    float* wl0 = wbuf + (wvu << 10);     // wave's w chunk base

    float acc[16];
#pragma unroll
    for (int e = 0; e < 16; ++e) acc[e] = 0.f;

    // ---- per-lane read bases (r5-identical)
    const int t0 = (tt << 5) + (ta << 2);           // token base within block
    const float* xq0 = xbuf + ((t0 + 0) << 8) + (kq << 6);
    const float* xq1 = xbuf + ((t0 + 1) << 8) + (kq << 6);
    const float* xq2 = xbuf + ((t0 + 2) << 8) + (kq << 6);
    const float* xq3 = xbuf + ((t0 + 3) << 8) + (kq << 6);
    const int c0 = (t0 + 0) & 15, c1 = (t0 + 1) & 15;
    const int c2 = (t0 + 2) & 15, c3 = (t0 + 3) & 15;
    const int ebase = (te << 5) + (eb << 2);        // expert base within block
    const float* wbase = wbuf + (kq << 12) + ebase; // + (m*4+u)*64 (imm)

    // ---- stage step 0, then 2 barriers per step (compiler drains vmcnt
    //      before each s_barrier, which covers the global_load_lds queue)
    {
        const float* xp = gxB;
        gl_lds16(xp +        ((g0 ^ 0) << 2), xl0);
        gl_lds16(xp + 1024 + ((g0 ^ 1) << 2), xl0 + 256);
        gl_lds16(xp + 2048 + ((g0 ^ 2) << 2), xl0 + 512);
        gl_lds16(xp + 3072 + ((g0 ^ 3) << 2), xl0 + 768);
        gl_lds16(gwB,       wl0);
        gl_lds16(gwB + 256, wl0 + 256);
        gl_lds16(gwB + 512, wl0 + 512);
        gl_lds16(gwB + 768, wl0 + 768);
    }
    __syncthreads();

#pragma unroll 1
    for (int s = 0; s < 4; ++s) {
#pragma unroll
        for (int m = 0; m < 16; ++m) {
            float4 xf0 = *(const float4*)(xq0 + (((m ^ c0) & 15) << 2));
            float4 xf1 = *(const float4*)(xq1 + (((m ^ c1) & 15) << 2));
            float4 xf2 = *(const float4*)(xq2 + (((m ^ c2) & 15) << 2));
            float4 xf3 = *(const float4*)(xq3 + (((m ^ c3) & 15) << 2));
            const float* wq = wbase + (m << 8);
            float4 wf0 = *(const float4*)(wq);
            float4 wf1 = *(const float4*)(wq + 64);
            float4 wf2 = *(const float4*)(wq + 128);
            float4 wf3 = *(const float4*)(wq + 192);
            float xa[16] = {xf0.x, xf0.y, xf0.z, xf0.w,
                            xf1.x, xf1.y, xf1.z, xf1.w,
                            xf2.x, xf2.y, xf2.z, xf2.w,
                            xf3.x, xf3.y, xf3.z, xf3.w};
            float wa[16] = {wf0.x, wf0.y, wf0.z, wf0.w,
                            wf1.x, wf1.y, wf1.z, wf1.w,
                            wf2.x, wf2.y, wf2.z, wf2.w,
                            wf3.x, wf3.y, wf3.z, wf3.w};
#pragma unroll
            for (int i = 0; i < 4; ++i)
#pragma unroll
                for (int u = 0; u < 4; ++u) {
                    float xv = xa[(i << 2) + u];
#pragma unroll
                    for (int j = 0; j < 4; ++j)
                        acc[(i << 2) + j] = fmaf(xv, wa[(u << 2) + j], acc[(i << 2) + j]);
                }
        }
        if (s < 3) {
            __syncthreads();                        // all reads of slab done
            const float* xp = gxB + ((s + 1) << 6);
            gl_lds16(xp +        ((g0 ^ 0) << 2), xl0);
            gl_lds16(xp + 1024 + ((g0 ^ 1) << 2), xl0 + 256);
            gl_lds16(xp + 2048 + ((g0 ^ 2) << 2), xl0 + 512);
            gl_lds16(xp + 3072 + ((g0 ^ 3) << 2), xl0 + 768);
            const float* wp2 = gwB + ((s + 1) << 12);
            gl_lds16(wp2,       wl0);
            gl_lds16(wp2 + 256, wl0 + 256);
            gl_lds16(wp2 + 512, wl0 + 512);
            gl_lds16(wp2 + 768, wl0 + 768);
            __syncthreads();                        // DMA drained -> slab ready
        }
    }

    // ---- combine 4 k-quarter partials into sc (barrier chain over kq)
    __syncthreads();
    if (kq == 0) {
#pragma unroll
        for (int i = 0; i < 4; ++i) {
            float4 v = make_float4(acc[(i << 2)], acc[(i << 2) + 1],
                                   acc[(i << 2) + 2], acc[(i << 2) + 3]);
            *(float4*)(sc + (t0 + i) * 68 + ebase) = v;
        }
    }
    __syncthreads();
    if (kq == 1) {
#pragma unroll
        for (int i = 0; i < 4; ++i) {
            float4 o = *(float4*)(sc + (t0 + i) * 68 + ebase);
            o.x += acc[(i << 2)];     o.y += acc[(i << 2) + 1];
            o.z += acc[(i << 2) + 2]; o.w += acc[(i << 2) + 3];
            *(float4*)(sc + (t0 + i) * 68 + ebase) = o;
        }
    }
    __syncthreads();
    if (kq == 2) {
#pragma unroll
        for (int i = 0; i < 4; ++i) {
            float4 o = *(float4*)(sc + (t0 + i) * 68 + ebase);
            o.x += acc[(i << 2)];     o.y += acc[(i << 2) + 1];
            o.z += acc[(i << 2) + 2]; o.w += acc[(i << 2) + 3];
            *(float4*)(sc + (t0 + i) * 68 + ebase) = o;
        }
    }
    __syncthreads();
    if (kq == 3) {
#pragma unroll
        for (int i = 0; i < 4; ++i) {
            float4 o = *(float4*)(sc + (t0 + i) * 68 + ebase);
            o.x += acc[(i << 2)];     o.y += acc[(i << 2) + 1];
            o.z += acc[(i << 2) + 2]; o.w += acc[(i << 2) + 3];
            *(float4*)(sc + (t0 + i) * 68 + ebase) = o;
        }
    }
    __syncthreads();

    // ---- per-token epilogue (serial, proven absmax 0)
    if (tid < 64) {
        const int r = tid;
        const float* srow = sc + r * 68;
        float v1 = -1e30f, v2 = -1e30f;
        int i1 = 0, i2 = 0;
        for (int j = 0; j < 64; ++j) {
            float l = srow[j];
            if (l > v1)      { v2 = v1; i2 = i1; v1 = l; i1 = j; }
            else if (l > v2) { v2 = l; i2 = j; }
        }
        float m = v1;
        float ssum = 0.f;
        for (int j = 0; j < 64; ++j) {
            float ev = expf(srow[j] - m);
            ssum += ev;
            sc[r * 68 + j] = ev;
        }
        float inv = 1.f / ssum;
        row_inv[r] = inv;
        float z = m + logf(ssum);
        float zsq = z * z;
#pragma unroll
        for (int off = 32; off > 0; off >>= 1) zsq += __shfl_down(zsq, off);
        if (lane == 0) atomicAdd(acc_ws + 64, zsq);

        float p1s = inv;                        // exp(v1-m) == 1
        float p2s = expf(v2 - m) * inv;
        float bb  = expf(p2s - p1s);
        float s1 = 1.f / (1.f + bb);
        float s2 = bb * s1;
        int t = tok0 + r;
        out[2 * t]     = s1;
        out[2 * t + 1] = s2;
        out[2 * T_TOK + 2 * t]     = (float)i1;
        out[2 * T_TOK + 2 * t + 1] = (float)i2;
    }
    __syncthreads();

    // ---- expert load column sums (16 row-groups of 4 rows)
    {
        int e  = tid & 63;
        int rg = tid >> 6;                      // 0..15
        float sum = 0.f;
#pragma unroll
        for (int r2 = 0; r2 < 4; ++r2) {
            int row = (rg << 2) + r2;
            sum += sc[row * 68 + e] * row_inv[row];
        }
        colpart[rg][e] = sum;
    }
    __syncthreads();
    if (tid < 64) {
        float tot = 0.f;
#pragma unroll
        for (int rg = 0; rg < 16; ++rg) tot += colpart[rg][tid];
        atomicAdd(acc_ws + tid, tot);           // device-scope
    }

    // ---- last-block finalize
    __syncthreads();
    if (tid == 0) {
        __threadfence();
        int old = __hip_atomic_fetch_add((int*)(acc_ws + 66), 1,
                                         __ATOMIC_ACQ_REL, __HIP_MEMORY_SCOPE_AGENT);
        is_last = (old == 255) ? 1 : 0;
    }
    __syncthreads();
    if (is_last && tid < 64) {
        __threadfence();
        float load = __hip_atomic_load(acc_ws + tid, __ATOMIC_RELAXED,
                                       __HIP_MEMORY_SCOPE_AGENT) * (1.f / 16384.f);
        float d = load - (1.f / 64.f);
        float v = d * d;
#pragma unroll
        for (int off = 32; off > 0; off >>= 1) v += __shfl_down(v, off);
        if (tid == 0) {
            float zsum = __hip_atomic_load(acc_ws + 64, __ATOMIC_RELAXED,
                                           __HIP_MEMORY_SCOPE_AGENT);
            float lb = 0.01f * 64.f * v;
            float zl = 1e-4f * zsum * (1.f / 16384.f);
            out[4 * T_TOK] = lb + zl;
        }
    }
}

extern "C" void kernel_launch(void* const* d_in, const int* in_sizes, int n_in,
                              void* d_out, int out_size, void* d_ws, size_t ws_size,
                              hipStream_t stream) {
    const float* x  = (const float*)d_in[0];   // [4,4096,1024] fp32
    const float* gw = (const float*)d_in[1];   // [64,1024] fp32
    float* out = (float*)d_out;                // 65537 fp32
    float* ws  = (float*)d_ws;

    moe_prep<<<16, 256, 0, stream>>>(gw, ws);
    moe_main<<<256, 1024, 0, stream>>>(x, ws + 128, ws, out);
}

// Round 8
// 128.664 us; speedup vs baseline: 7.3836x; 7.3836x over previous
//
#include <hip/hip_runtime.h>
#include <math.h>

#define T_TOK 16384   // 4*4096 tokens
#define NEXP  64

// Workspace layout (floats):
//   ws[0..63]   : expert load sums
//   ws[64]      : sum of z^2
//   ws[66]      : block-done counter (int)
//   ws[128 ..]  : w_t transposed gate weights [1024][64]
//
// d_out layout (floats, out_size = 65537):
//   [0, 32768)      top-2 renormalized scores [token][2]
//   [32768, 65536)  top-2 expert indices as floats [token][2]
//   [65536]         total_loss

// ---------------------------------------------------------------------------
// prep: tiled transpose gate_w [64][1024] -> w_t [1024][64]; zero accumulators
// ---------------------------------------------------------------------------
__global__ void moe_prep(const float* __restrict__ gw, float* __restrict__ ws) {
    __shared__ float tile[64][65];
    const int b = blockIdx.x;
    const int tid = threadIdx.x;         // 256
    if (b == 0 && tid < 128) ws[tid] = 0.f;
#pragma unroll
    for (int it = 0; it < 16; ++it) {
        int idx = it * 256 + tid;
        int e = idx >> 6, kk = idx & 63;
        tile[e][kk] = gw[e * 1024 + b * 64 + kk];
    }
    __syncthreads();
#pragma unroll
    for (int it = 0; it < 16; ++it) {
        int idx = it * 256 + tid;
        int kk = idx >> 6, e = idx & 63;
        ws[128 + (b * 64 + kk) * 64 + e] = tile[e][kk];
    }
}

// ---------------------------------------------------------------------------
// fold helpers: store/add a lane's 4t x 8e partial into a stride-68 buffer.
// rows t0..t0+3 (consecutive), cols eb*8..+7 (two float4).
// ---------------------------------------------------------------------------
__device__ __forceinline__ void pst8(float* B, const float (&a)[4][8],
                                     int t0, int eb) {
#pragma unroll
    for (int i = 0; i < 4; ++i) {
        float* p = B + (t0 + i) * 68 + (eb << 3);
        *(float4*)(p)     = make_float4(a[i][0], a[i][1], a[i][2], a[i][3]);
        *(float4*)(p + 4) = make_float4(a[i][4], a[i][5], a[i][6], a[i][7]);
    }
}
__device__ __forceinline__ void pad8(float* B, const float (&a)[4][8],
                                     int t0, int eb) {
#pragma unroll
    for (int i = 0; i < 4; ++i) {
        float* p = B + (t0 + i) * 68 + (eb << 3);
        float4 v0 = *(float4*)(p);
        float4 v1 = *(float4*)(p + 4);
        v0.x += a[i][0]; v0.y += a[i][1]; v0.z += a[i][2]; v0.w += a[i][3];
        v1.x += a[i][4]; v1.y += a[i][5]; v1.z += a[i][6]; v1.w += a[i][7];
        *(float4*)(p)     = v0;
        *(float4*)(p + 4) = v1;
    }
}

// ---------------------------------------------------------------------------
// main: LDS-byte-halved fp32 GEMM. R0-R7 synthesis: the wall is the per-CU
// LDS read pipe (R0: 512 KB/step -> ~6100 cyc/step; measured 8000). Fix:
// per-lane tile 4t x 8e -> 1.5 B/FMA (was 2.0): per step per CU
// 16 waves x (16 ds_read_b64 + 8 ds_read_b128) ~= 3072 cyc. acc=32 regs +
// xa8 + wa8 + pf8 fits the environment's hard 64-VGPR cap (no shuffles;
// tripwire = WRITE_SIZE). Waves: tt (2 token halves) x kq (8 k-eighths);
// K_STEP=64, R0's proven 2-barrier step + register prefetch.
// Bank audit: x slab [64t][16 slots], slot = chunk ^ ((row&3)<<2 | (row>>2)&3)
// mixes ta (lane-varying) into slot bits 0-1 -> 8 ta lanes hit 4 bank-pairs
// (2-way = free). w slab [64k][64e] straight: 8 lanes x 32B = 2-way (free).
// Fold: 8 kq-partials via two parallel chains + merge; epilogue verbatim.
// ---------------------------------------------------------------------------
__launch_bounds__(1024, 1)
__global__ void moe_main(const float* __restrict__ x,
                         const float* __restrict__ wt,     // [1024][64]
                         float* __restrict__ acc_ws,
                         float* __restrict__ out) {
    __shared__ float xbuf[64 * 64];      // x slab: [t 64][slot 16][4] swizzled
    __shared__ float wbuf[64 * 64];      // w slab: [k 64][e 64] straight
    __shared__ float sc[64 * 68];        // logits, stride 68
    __shared__ float fb[64 * 68];        // fold scratch, stride 68
    __shared__ float row_inv[64];
    __shared__ float colpart[16][64];
    __shared__ int   is_last;

    const int tid  = threadIdx.x;
    const int lane = tid & 63;
    const int wv   = tid >> 6;                                   // 0..15
    const int kq   = __builtin_amdgcn_readfirstlane(wv & 7);     // k eighth
    const int tt   = __builtin_amdgcn_readfirstlane(wv >> 3);    // token half
    const int ta = lane >> 3;            // token-quad within half (0..7)
    const int eb = lane & 7;             // expert-octet (0..7)
    const int tok0 = blockIdx.x << 6;

    // ---- staging plan (1024 threads, 1 float4 x + 1 float4 w per step)
    // x: thread (rr, cg): global k = s*64 + cg*4, stored at swizzled slot
    //    cg ^ rm2(rr), rm2(r) = ((r&3)<<2) | ((r>>2)&3)
    const int rr = tid >> 4;             // 0..63
    const int cg = tid & 15;
    const float* gx = x + (((size_t)(tok0 + rr)) << 10) + (cg << 2);
    const int rm2s = ((rr & 3) << 2) | ((rr >> 2) & 3);
    const int xlo = (rr << 6) + ((cg ^ rm2s) << 2);
    // w: slab row rr = local k; global k-row = s*64 + rr
    const float* gw = wt + (rr << 6) + (cg << 2);
    const int wlo = (rr << 6) + (cg << 2);

    float acc[4][8];
#pragma unroll
    for (int i = 0; i < 4; ++i)
#pragma unroll
        for (int j = 0; j < 8; ++j) acc[i][j] = 0.f;

    // ---- per-lane read bases
    const int t0 = (tt << 5) + (ta << 2);           // token base (rows t0..t0+3)
    // per-row swizzle masks: row = t0+i -> row&3 = i, (row>>2)&3 = (tt*8+ta)&3
    const int rhi = (t0 >> 2) & 3;                  // = (tt*8+ta)&3, lane-varying
    // x read offset for row i, chunk c, half sub:
    //   (t0+i)*64 + ((c ^ ((i<<2)|rhi)) << 2) + (sub<<1)
    const int ebase = eb << 3;                      // expert octet base

    // prologue prefetch of step 0
    float4 px = *(const float4*)gx;
    float4 pw = *(const float4*)gw;

#pragma unroll 1
    for (int s = 0; s < 16; ++s) {
        __syncthreads();                            // bufs free
        *(float4*)(xbuf + xlo) = px;
        *(float4*)(wbuf + wlo) = pw;
        __syncthreads();                            // bufs ready
        if (s < 15) {                               // prefetch next step
            px = *(const float4*)(gx + ((s + 1) << 6));
            pw = *(const float4*)(gw + ((s + 1) << 12));
        }
#pragma unroll
        for (int kp = 0; kp < 4; ++kp) {            // k-pair within eighth
            const int c   = (kq << 1) + (kp >> 1);  // chunk (uniform)
            const int sub = kp & 1;                 // half within chunk
            float2 xf0, xf1, xf2, xf3;
            {
                const int b0 = ((t0 + 0) << 6) + ((c ^ ((0 << 2) | rhi)) << 2) + (sub << 1);
                const int b1 = ((t0 + 1) << 6) + ((c ^ ((1 << 2) | rhi)) << 2) + (sub << 1);
                const int b2 = ((t0 + 2) << 6) + ((c ^ ((2 << 2) | rhi)) << 2) + (sub << 1);
                const int b3 = ((t0 + 3) << 6) + ((c ^ ((3 << 2) | rhi)) << 2) + (sub << 1);
                xf0 = *(const float2*)(xbuf + b0);
                xf1 = *(const float2*)(xbuf + b1);
                xf2 = *(const float2*)(xbuf + b2);
                xf3 = *(const float2*)(xbuf + b3);
            }
#pragma unroll
            for (int h = 0; h < 2; ++h) {
                const int rk = (kq << 3) + (kp << 1) + h;   // local k row
                const float* wr = wbuf + (rk << 6) + ebase;
                float4 w0 = *(const float4*)(wr);
                float4 w1 = *(const float4*)(wr + 4);
                float wa[8] = {w0.x, w0.y, w0.z, w0.w, w1.x, w1.y, w1.z, w1.w};
                float xv0 = h ? xf0.y : xf0.x;
                float xv1 = h ? xf1.y : xf1.x;
                float xv2 = h ? xf2.y : xf2.x;
                float xv3 = h ? xf3.y : xf3.x;
#pragma unroll
                for (int j = 0; j < 8; ++j) {
                    acc[0][j] = fmaf(xv0, wa[j], acc[0][j]);
                    acc[1][j] = fmaf(xv1, wa[j], acc[1][j]);
                    acc[2][j] = fmaf(xv2, wa[j], acc[2][j]);
                    acc[3][j] = fmaf(xv3, wa[j], acc[3][j]);
                }
            }
        }
    }

    // ---- fold 8 kq-partials (per tt half) via 2 parallel chains + merge
    if      (kq == 0) pst8(sc, acc, t0, eb);
    else if (kq == 1) pst8(fb, acc, t0, eb);
    __syncthreads();
    if      (kq == 2) pad8(sc, acc, t0, eb);
    else if (kq == 3) pad8(fb, acc, t0, eb);
    __syncthreads();
    if      (kq == 4) pad8(sc, acc, t0, eb);
    else if (kq == 5) pad8(fb, acc, t0, eb);
    __syncthreads();
    if      (kq == 6) pad8(sc, acc, t0, eb);
    else if (kq == 7) pad8(fb, acc, t0, eb);
    __syncthreads();
    {   // sc += fb (vectorized, all 1024 threads; 64 rows x 16 granules)
        const int row = tid >> 4, g = tid & 15;
        float* ps = sc + row * 68 + (g << 2);
        float4 a  = *(float4*)ps;
        float4 bx = *(const float4*)(fb + row * 68 + (g << 2));
        a.x += bx.x; a.y += bx.y; a.z += bx.z; a.w += bx.w;
        *(float4*)ps = a;
    }
    __syncthreads();

    // ---- per-token epilogue (serial, proven absmax 0)
    if (tid < 64) {
        const int r = tid;
        const float* srow = sc + r * 68;
        float v1 = -1e30f, v2 = -1e30f;
        int i1 = 0, i2 = 0;
        for (int j = 0; j < 64; ++j) {
            float l = srow[j];
            if (l > v1)      { v2 = v1; i2 = i1; v1 = l; i1 = j; }
            else if (l > v2) { v2 = l; i2 = j; }
        }
        float m = v1;
        float ssum = 0.f;
        for (int j = 0; j < 64; ++j) {
            float ev = expf(srow[j] - m);
            ssum += ev;
            sc[r * 68 + j] = ev;
        }
        float inv = 1.f / ssum;
        row_inv[r] = inv;
        float z = m + logf(ssum);
        float zsq = z * z;
#pragma unroll
        for (int off = 32; off > 0; off >>= 1) zsq += __shfl_down(zsq, off);
        if (lane == 0) atomicAdd(acc_ws + 64, zsq);

        float p1s = inv;                        // exp(v1-m) == 1
        float p2s = expf(v2 - m) * inv;
        float bb  = expf(p2s - p1s);
        float s1 = 1.f / (1.f + bb);
        float s2 = bb * s1;
        int t = tok0 + r;
        out[2 * t]     = s1;
        out[2 * t + 1] = s2;
        out[2 * T_TOK + 2 * t]     = (float)i1;
        out[2 * T_TOK + 2 * t + 1] = (float)i2;
    }
    __syncthreads();

    // ---- expert load column sums (16 row-groups of 4 rows)
    {
        int e  = tid & 63;
        int rg = tid >> 6;                      // 0..15
        float sum = 0.f;
#pragma unroll
        for (int r2 = 0; r2 < 4; ++r2) {
            int row = (rg << 2) + r2;
            sum += sc[row * 68 + e] * row_inv[row];
        }
        colpart[rg][e] = sum;
    }
    __syncthreads();
    if (tid < 64) {
        float tot = 0.f;
#pragma unroll
        for (int rg = 0; rg < 16; ++rg) tot += colpart[rg][tid];
        atomicAdd(acc_ws + tid, tot);           // device-scope
    }

    // ---- last-block finalize
    __syncthreads();
    if (tid == 0) {
        __threadfence();
        int old = __hip_atomic_fetch_add((int*)(acc_ws + 66), 1,
                                         __ATOMIC_ACQ_REL, __HIP_MEMORY_SCOPE_AGENT);
        is_last = (old == 255) ? 1 : 0;
    }
    __syncthreads();
    if (is_last && tid < 64) {
        __threadfence();
        float load = __hip_atomic_load(acc_ws + tid, __ATOMIC_RELAXED,
                                       __HIP_MEMORY_SCOPE_AGENT) * (1.f / 16384.f);
        float d = load - (1.f / 64.f);
        float v = d * d;
#pragma unroll
        for (int off = 32; off > 0; off >>= 1) v += __shfl_down(v, off);
        if (tid == 0) {
            float zsum = __hip_atomic_load(acc_ws + 64, __ATOMIC_RELAXED,
                                           __HIP_MEMORY_SCOPE_AGENT);
            float lb = 0.01f * 64.f * v;
            float zl = 1e-4f * zsum * (1.f / 16384.f);
            out[4 * T_TOK] = lb + zl;
        }
    }
}

extern "C" void kernel_launch(void* const* d_in, const int* in_sizes, int n_in,
                              void* d_out, int out_size, void* d_ws, size_t ws_size,
                              hipStream_t stream) {
    const float* x  = (const float*)d_in[0];   // [4,4096,1024] fp32
    const float* gw = (const float*)d_in[1];   // [64,1024] fp32
    float* out = (float*)d_out;                // 65537 fp32
    float* ws  = (float*)d_ws;

    moe_prep<<<16, 256, 0, stream>>>(gw, ws);
    moe_main<<<256, 1024, 0, stream>>>(x, ws + 128, ws, out);
}